// Round 1
// baseline (194.411 us; speedup 1.0000x reference)
//
#include <hip/hip_runtime.h>
#include <hip/hip_bf16.h>

typedef __attribute__((ext_vector_type(8))) short bf16x8;   // 8 bf16 = 4 VGPR
typedef __attribute__((ext_vector_type(4))) float f32x4;
typedef unsigned int u32;

#define MOD_SCALE 0.04419417382415922f     // 1/sqrt(512)
#define CONV_SCALE 0.014731391274719742f   // 1/sqrt(512*9)

__device__ __forceinline__ unsigned short f2bf(float f) {
  union { float f; u32 u; } v; v.f = f;
  u32 r = v.u + 0x7fffu + ((v.u >> 16) & 1u);   // RNE
  return (unsigned short)(r >> 16);
}

__device__ __forceinline__ void gload_lds16(const void* g, void* l) {
  __builtin_amdgcn_global_load_lds(
      (const __attribute__((address_space(1))) u32*)g,
      (__attribute__((address_space(3))) u32*)l, 16, 0, 0);
}

// ---- k1: s[b][ic] = MOD_SCALE * (style[b] . mod_weight[ic]) + mod_bias[ic]
__global__ void k_style(const float* __restrict__ style, const float* __restrict__ mw,
                        const float* __restrict__ mb, float* __restrict__ s) {
  int idx = blockIdx.x * 256 + threadIdx.x;   // 4096 = b*512+ic
  int b = idx >> 9, ic = idx & 511;
  const float4* wr = (const float4*)(mw + ic * 512);
  const float4* sr = (const float4*)(style + b * 512);
  float acc = 0.f;
  #pragma unroll 4
  for (int k = 0; k < 128; ++k) {
    float4 a = wr[k], c = sr[k];
    acc += a.x * c.x + a.y * c.y + a.z * c.z + a.w * c.w;
  }
  s[idx] = acc * MOD_SCALE + mb[ic];
}

// ---- k2: wb[tap][oc][ic] = bf16(w), wsq[oc][ic] = sum_tap w^2, zero scratch line
__global__ void k_wprep(const float* __restrict__ wsrc, ushort* __restrict__ wb,
                        float* __restrict__ wsq, float* __restrict__ zerobuf) {
  int idx = blockIdx.x * 256 + threadIdx.x;   // 262144 = oc*512+ic
  if (blockIdx.x == 0 && threadIdx.x < 16) zerobuf[threadIdx.x] = 0.f;
  const float* wp = wsrc + (size_t)idx * 9;
  float sq = 0.f;
  #pragma unroll
  for (int tap = 0; tap < 9; ++tap) {
    float v = wp[tap];
    sq += v * v;
    wb[tap * 262144 + idx] = f2bf(v);
  }
  wsq[idx] = sq;
}

// ---- k3: dscale[b][oc] = CONV_SCALE * rsqrt(CONV_SCALE^2 * sum_ic wsq*s^2 + eps)
__global__ void k_demod(const float* __restrict__ wsq, const float* __restrict__ s,
                        float* __restrict__ dscale) {
  int idx = blockIdx.x * 256 + threadIdx.x;   // 4096 = b*512+oc
  int b = idx >> 9, oc = idx & 511;
  const float4* wq = (const float4*)(wsq + oc * 512);
  const float4* sp = (const float4*)(s + b * 512);
  float acc = 0.f;
  #pragma unroll 4
  for (int k = 0; k < 128; ++k) {
    float4 a = wq[k], c = sp[k];
    acc += a.x * c.x * c.x + a.y * c.y * c.y + a.z * c.z * c.z + a.w * c.w * c.w;
  }
  dscale[idx] = CONV_SCALE * rsqrtf(CONV_SCALE * CONV_SCALE * acc + 1e-8f);
}

// ---- k4: xsb[b][y][x][ic] = bf16(x[b][ic][y][x] * s[b][ic])  (NCHW->NHWC)
__global__ void k_xform(const float* __restrict__ x, const float* __restrict__ s,
                        ushort* __restrict__ xsb) {
  const int y = blockIdx.x, icb = blockIdx.y, b = blockIdx.z;
  const int t = threadIdx.x;
  __shared__ ushort tile[64][67];
  const int px = t & 63, icq = t >> 6;
  #pragma unroll
  for (int i = 0; i < 16; ++i) {
    int ic_l = i * 4 + icq;
    int ic = icb * 64 + ic_l;
    float v = x[(b * 512 + ic) * 4096 + y * 64 + px] * s[b * 512 + ic];
    tile[ic_l][px] = f2bf(v);
  }
  __syncthreads();
  const int kp = t & 31, pq = t >> 5;
  ushort* obase = xsb + ((b * 64 + y) * 64) * 512 + icb * 64 + kp * 2;
  #pragma unroll
  for (int i = 0; i < 8; ++i) {
    int p = i * 8 + pq;
    ushort2 u;
    u.x = tile[kp * 2][p];
    u.y = tile[kp * 2 + 1][p];
    *(ushort2*)(obase + p * 512) = u;
  }
}

// ---- k5: implicit-GEMM conv.
// Block: 64 oc x (4 rows x 64 px). 4 waves, wave = one output row, 4x4 frags of
// mfma_f32_16x16x32_bf16. K-loop: ic in steps of 32; 9 taps share one staged
// window Bs[6 rows][66 cols][32 ic]. A = wb tiles As[9][64 oc][32 ic].
// 16B chunks are XOR-swizzled (slot q stored from source chunk q^((col>>1)&3))
// so stride-64B fragment reads land on 8 distinct 16B slots per 8 lanes (2-way).
__global__ __launch_bounds__(256, 2) void k_conv(
    const ushort* __restrict__ wb, const ushort* __restrict__ xsb,
    const float* __restrict__ dscale, const float* __restrict__ zerobuf,
    float* __restrict__ out) {
  const int yb = blockIdx.x, ocb = blockIdx.y, b = blockIdx.z;
  const int t = threadIdx.x;
  const int wv = t >> 6, l = t & 63;
  const int ln = l & 15, lq = l >> 4;
  const int y0 = yb * 4;

  __shared__ __align__(16) ushort As[9 * 64 * 32];   // 36864 B
  __shared__ __align__(16) ushort Bs[6 * 66 * 32];   // 25344 B
  __shared__ float dss[64];

  if (t < 64) dss[t] = dscale[b * 512 + ocb * 64 + t];

  f32x4 acc[4][4];
  #pragma unroll
  for (int m = 0; m < 4; ++m)
    #pragma unroll
    for (int n = 0; n < 4; ++n)
      acc[m][n] = f32x4{0.f, 0.f, 0.f, 0.f};

  const int aslot = lq ^ ((ln >> 1) & 3);
  int bslot[3];
  #pragma unroll
  for (int dx = 0; dx < 3; ++dx) bslot[dx] = lq ^ (((ln + dx) >> 1) & 3);

  // A staging: iter i = tap; thread t -> oc_l = t>>2, chunk q = t&3 (swizzled src)
  const int a_ocl = t >> 2, a_q = t & 3;
  const int a_qs = a_q ^ ((a_ocl >> 1) & 3);
  const char* srcA0 = (const char*)(wb + (ocb * 64 + a_ocl) * 512 + a_qs * 8);
  char* ldsA0 = (char*)As + wv * 1024;

  // B staging geometry (static per thread): cid = i*256+t -> (row r, col c, chunk q)
  int bvalid[7];
  const char* bsrc_base[7];
  char* bdst[7];
  #pragma unroll
  for (int i = 0; i < 7; ++i) {
    int cid = i * 256 + t;
    int r = cid / 264;              // 264 = 66 cols * 4 chunks
    int rem = cid - r * 264;
    int c = rem >> 2, q = rem & 3;
    int yy = y0 - 1 + r, xx = c - 1;
    int qs = q ^ ((c >> 1) & 3);
    bvalid[i] = (cid < 1584) && ((unsigned)yy < 64u) && ((unsigned)xx < 64u);
    bsrc_base[i] = bvalid[i]
        ? (const char*)(xsb + ((b * 64 + yy) * 64 + xx) * 512 + qs * 8)
        : (const char*)zerobuf;
    bdst[i] = (char*)Bs + (i * 256 + wv * 64) * 16;
  }

  #pragma unroll 1
  for (int icb_i = 0; icb_i < 16; ++icb_i) {
    const int icB = icb_i * 64;   // ic0 * 2 bytes
    // ---- stage A: 9 x global_load_lds(16B) per thread
    #pragma unroll
    for (int i = 0; i < 9; ++i)
      gload_lds16(srcA0 + i * 524288 + icB, ldsA0 + i * 4096);
    // ---- stage B: 6 full + 1 partial iter
    #pragma unroll
    for (int i = 0; i < 7; ++i) {
      if (i < 6 || t < 48) {
        const char* src = bvalid[i] ? bsrc_base[i] + icB : (const char*)zerobuf;
        gload_lds16(src, bdst[i]);
      }
    }
    __syncthreads();
    // ---- compute: 9 taps x (4 A-frags + 4 B-frags -> 16 mfma)
    #pragma unroll
    for (int dy = 0; dy < 3; ++dy) {
      const int r = wv + dy;
      #pragma unroll
      for (int dx = 0; dx < 3; ++dx) {
        const int tap = dy * 3 + dx;
        bf16x8 af[4], bfr[4];
        #pragma unroll
        for (int m = 0; m < 4; ++m)
          af[m] = *(const bf16x8*)((const char*)As + tap * 4096 + (m * 16 + ln) * 64 + aslot * 16);
        #pragma unroll
        for (int n = 0; n < 4; ++n) {
          int c = n * 16 + ln + dx;
          bfr[n] = *(const bf16x8*)((const char*)Bs + (r * 66 + c) * 64 + bslot[dx] * 16);
        }
        #pragma unroll
        for (int m = 0; m < 4; ++m)
          #pragma unroll
          for (int n = 0; n < 4; ++n)
            acc[m][n] = __builtin_amdgcn_mfma_f32_16x16x32_bf16(af[m], bfr[n], acc[m][n], 0, 0, 0);
      }
    }
    __syncthreads();
  }

  // ---- epilogue: D[row][col]: row = lq*4+reg (oc), col = ln (px)   [m89 layout]
  const int y_row = y0 + wv;
  #pragma unroll
  for (int m = 0; m < 4; ++m) {
    #pragma unroll
    for (int r4 = 0; r4 < 4; ++r4) {
      const int oc_l = m * 16 + lq * 4 + r4;
      const float sc = dss[oc_l];
      float* op = out + ((b * 512 + ocb * 64 + oc_l) * 4096 + y_row * 64);
      #pragma unroll
      for (int n = 0; n < 4; ++n)
        op[n * 16 + ln] = acc[m][n][r4] * sc;
    }
  }
}

extern "C" void kernel_launch(void* const* d_in, const int* in_sizes, int n_in,
                              void* d_out, int out_size, void* d_ws, size_t ws_size,
                              hipStream_t stream) {
  const float* x     = (const float*)d_in[0];  // [8,512,64,64]
  const float* style = (const float*)d_in[1];  // [8,512]
  const float* mw    = (const float*)d_in[2];  // [512,512]
  const float* mb    = (const float*)d_in[3];  // [512]
  const float* wsrc  = (const float*)d_in[4];  // [1,512,512,3,3]
  float* out = (float*)d_out;

  char* ws = (char*)d_ws;
  float*  zerobuf = (float*)(ws + 0);          //    64 B (16 f32)
  float*  s       = (float*)(ws + 256);        //  16 KB
  float*  dscale  = (float*)(ws + 16640);      //  16 KB
  float*  wsq     = (float*)(ws + 33024);      //   1 MB
  ushort* wb      = (ushort*)(ws + 1081600);   // 4.5 MB  [9][512][512] bf16
  ushort* xsb     = (ushort*)(ws + 5800192);   //  32 MB  [8][64][64][512] bf16

  k_style<<<dim3(16), dim3(256), 0, stream>>>(style, mw, mb, s);
  k_wprep<<<dim3(1024), dim3(256), 0, stream>>>(wsrc, wb, wsq, zerobuf);
  k_demod<<<dim3(16), dim3(256), 0, stream>>>(wsq, s, dscale);
  k_xform<<<dim3(64, 8, 8), dim3(256), 0, stream>>>(x, s, xsb);
  k_conv<<<dim3(16, 8, 8), dim3(256), 0, stream>>>(wb, xsb, dscale, zerobuf, out);
}

// Round 2
// 190.196 us; speedup vs baseline: 1.0222x; 1.0222x over previous
//
#include <hip/hip_runtime.h>
#include <hip/hip_bf16.h>

typedef __attribute__((ext_vector_type(8))) short bf16x8;   // 8 bf16 = 4 VGPR
typedef __attribute__((ext_vector_type(4))) float f32x4;
typedef unsigned int u32;

#define MOD_SCALE 0.04419417382415922f     // 1/sqrt(512)
#define CONV_SCALE 0.014731391274719742f   // 1/sqrt(512*9)

__device__ __forceinline__ unsigned short f2bf(float f) {
  union { float f; u32 u; } v; v.f = f;
  u32 r = v.u + 0x7fffu + ((v.u >> 16) & 1u);   // RNE
  return (unsigned short)(r >> 16);
}

__device__ __forceinline__ void gload_lds16(const void* g, void* l) {
  __builtin_amdgcn_global_load_lds(
      (const __attribute__((address_space(1))) u32*)g,
      (__attribute__((address_space(3))) u32*)l, 16, 0, 0);
}

// ---- k1: s[b][ic] = MOD_SCALE * (style[b] . mod_weight[ic]) + mod_bias[ic]
__global__ void k_style(const float* __restrict__ style, const float* __restrict__ mw,
                        const float* __restrict__ mb, float* __restrict__ s) {
  int idx = blockIdx.x * 256 + threadIdx.x;   // 4096 = b*512+ic
  int b = idx >> 9, ic = idx & 511;
  const float4* wr = (const float4*)(mw + ic * 512);
  const float4* sr = (const float4*)(style + b * 512);
  float acc = 0.f;
  #pragma unroll 4
  for (int k = 0; k < 128; ++k) {
    float4 a = wr[k], c = sr[k];
    acc += a.x * c.x + a.y * c.y + a.z * c.z + a.w * c.w;
  }
  s[idx] = acc * MOD_SCALE + mb[ic];
}

// ---- k2: wb[tap][oc][ic] = bf16(w), wsq[oc][ic] = sum_tap w^2, zero scratch line
__global__ void k_wprep(const float* __restrict__ wsrc, ushort* __restrict__ wb,
                        float* __restrict__ wsq, float* __restrict__ zerobuf) {
  int idx = blockIdx.x * 256 + threadIdx.x;   // 262144 = oc*512+ic
  if (blockIdx.x == 0 && threadIdx.x < 16) zerobuf[threadIdx.x] = 0.f;
  const float* wp = wsrc + (size_t)idx * 9;
  float sq = 0.f;
  #pragma unroll
  for (int tap = 0; tap < 9; ++tap) {
    float v = wp[tap];
    sq += v * v;
    wb[tap * 262144 + idx] = f2bf(v);
  }
  wsq[idx] = sq;
}

// ---- k3: dscale[b][oc] = CONV_SCALE * rsqrt(CONV_SCALE^2 * sum_ic wsq*s^2 + eps)
__global__ void k_demod(const float* __restrict__ wsq, const float* __restrict__ s,
                        float* __restrict__ dscale) {
  int idx = blockIdx.x * 256 + threadIdx.x;   // 4096 = b*512+oc
  int b = idx >> 9, oc = idx & 511;
  const float4* wq = (const float4*)(wsq + oc * 512);
  const float4* sp = (const float4*)(s + b * 512);
  float acc = 0.f;
  #pragma unroll 4
  for (int k = 0; k < 128; ++k) {
    float4 a = wq[k], c = sp[k];
    acc += a.x * c.x * c.x + a.y * c.y * c.y + a.z * c.z * c.z + a.w * c.w * c.w;
  }
  dscale[idx] = CONV_SCALE * rsqrtf(CONV_SCALE * CONV_SCALE * acc + 1e-8f);
}

// ---- k4: xsb[b][y][x][ic] = bf16(x[b][ic][y][x] * s[b][ic])  (NCHW->NHWC)
// Block = (y, b, ich): 64px x 256ic. Per lane: gather 8 ic (8 coalesced f32 rows)
// -> one ds_write_b128 into T (row stride 528B spreads banks) -> b128 read + 16B store.
__global__ void k_xform(const float* __restrict__ x, const float* __restrict__ s,
                        ushort* __restrict__ xsb) {
  const int y = blockIdx.x, b = blockIdx.y, ich = blockIdx.z;
  const int t = threadIdx.x;
  __shared__ ushort T[64 * 264];          // 33792 B, row stride 264 ushort = 528 B
  const int px = t & 63, iq = t >> 6;
  const int icbase = ich * 256;
  #pragma unroll
  for (int i = 0; i < 8; ++i) {
    int ic8 = i * 4 + iq;                 // 0..31
    int ic0 = icbase + ic8 * 8;
    union { ushort u[8]; uint4 v; } pk;
    #pragma unroll
    for (int j = 0; j < 8; ++j) {
      int ic = ic0 + j;
      float v = x[(b * 512 + ic) * 4096 + y * 64 + px] * s[b * 512 + ic];
      pk.u[j] = f2bf(v);
    }
    *(uint4*)&T[px * 264 + ic8 * 8] = pk.v;
  }
  __syncthreads();
  const int ch = t & 31;
  ushort* obase = xsb + ((b * 64 + y) * 64) * 512 + icbase + ch * 8;
  #pragma unroll
  for (int i = 0; i < 8; ++i) {
    int p = i * 8 + (t >> 5);
    uint4 v = *(const uint4*)&T[p * 264 + ch * 8];
    *(uint4*)(obase + p * 512) = v;
  }
}

// ---- k5: implicit-GEMM conv, double-buffered (T3 minimum 2-phase).
// Block: 64 oc x (8 rows x 64 px), 512 threads = 8 waves, wave = one output row.
// Per K-step (32 ic): As[9 tap][64 oc][32 ic], Bs[10 rows][66 cols][32 ic],
// both double-buffered (2 x 79104 B). Stage(t+1) issued BEFORE compute(t);
// single __syncthreads per iter (its vmcnt(0) drain lands after the MFMA phase).
// 16B chunks XOR-swizzled on the SOURCE side; reads apply the same XOR (2-way max).
#define BUFB 79104
__global__ __launch_bounds__(512, 1) void k_conv(
    const ushort* __restrict__ wb, const ushort* __restrict__ xsb,
    const float* __restrict__ dscale, const float* __restrict__ zerobuf,
    float* __restrict__ out) {
  const int yb = blockIdx.x, ocb = blockIdx.y, b = blockIdx.z;
  const int t = threadIdx.x;
  const int wv = t >> 6, l = t & 63;
  const int ln = l & 15, lq = l >> 4;
  const int y0 = yb * 8;

  extern __shared__ char smem[];
  float* dss = (float*)(smem + 2 * BUFB);

  if (t < 64) dss[t] = dscale[b * 512 + ocb * 64 + t];

  f32x4 acc[4][4];
  #pragma unroll
  for (int m = 0; m < 4; ++m)
    #pragma unroll
    for (int n = 0; n < 4; ++n)
      acc[m][n] = f32x4{0.f, 0.f, 0.f, 0.f};

  const int aslot = lq ^ ((ln >> 1) & 3);
  int bslot[3];
  #pragma unroll
  for (int dx = 0; dx < 3; ++dx) bslot[dx] = lq ^ (((ln + dx) >> 1) & 3);

  // A staging: chunk cid = i*512+t -> tap = 2i+(t>>8) (i<4), tap 8 at i=4 (t<256)
  const int a_ocl = (t & 255) >> 2;
  const int a_qs = (t & 3) ^ ((a_ocl >> 1) & 3);
  const int a_tb = t >> 8;
  const char* srcA = (const char*)(wb + (ocb * 64 + a_ocl) * 512 + a_qs * 8);
  const int a_dstw = wv * 1024;        // wave-uniform LDS base within 512-chunk group

  // B staging: cid = i*512+t -> (row r, col c, chunk q); 2640 chunks total
  int bpart[6];
  const char* bsrc[6];
  int bdstc[6];
  #pragma unroll
  for (int i = 0; i < 6; ++i) {
    int cid = i * 512 + t;
    int r = cid / 264;
    int rem = cid - r * 264;
    int c = rem >> 2, q = rem & 3;
    int yy = y0 - 1 + r, xx = c - 1;
    int qs = q ^ ((c >> 1) & 3);
    bpart[i] = (cid < 2640);
    int geo_ok = bpart[i] && ((unsigned)yy < 64u) && ((unsigned)xx < 64u);
    bsrc[i] = geo_ok ? (const char*)(xsb + ((b * 64 + yy) * 64 + xx) * 512 + qs * 8)
                     : (const char*)nullptr;
    bdstc[i] = (i * 512 + wv * 64) * 16;
  }

  auto STAGE = [&](int boff, int icB) {
    char* Ab = smem + boff;
    char* Bb = smem + boff + 36864;
    #pragma unroll
    for (int i = 0; i < 4; ++i) {
      int tap = 2 * i + a_tb;
      gload_lds16(srcA + tap * 524288 + icB, Ab + i * 8192 + a_dstw);
    }
    if (t < 256)
      gload_lds16(srcA + 8 * 524288 + icB, Ab + 4 * 8192 + a_dstw);
    #pragma unroll
    for (int i = 0; i < 6; ++i) {
      if (bpart[i]) {
        const char* src = bsrc[i] ? bsrc[i] + icB : (const char*)zerobuf;
        gload_lds16(src, Bb + bdstc[i]);
      }
    }
  };

  auto COMPUTE = [&](int boff) {
    const char* Ab = smem + boff;
    const char* Bb = smem + boff + 36864;
    #pragma unroll
    for (int dy = 0; dy < 3; ++dy) {
      const int row = wv + dy;
      #pragma unroll
      for (int dx = 0; dx < 3; ++dx) {
        const int tap = dy * 3 + dx;
        bf16x8 af[4], bfr[4];
        #pragma unroll
        for (int m = 0; m < 4; ++m)
          af[m] = *(const bf16x8*)(Ab + tap * 4096 + (m * 16 + ln) * 64 + aslot * 16);
        #pragma unroll
        for (int n = 0; n < 4; ++n)
          bfr[n] = *(const bf16x8*)(Bb + (row * 66 + n * 16 + ln + dx) * 64 + bslot[dx] * 16);
        #pragma unroll
        for (int m = 0; m < 4; ++m)
          #pragma unroll
          for (int n = 0; n < 4; ++n)
            acc[m][n] = __builtin_amdgcn_mfma_f32_16x16x32_bf16(af[m], bfr[n], acc[m][n], 0, 0, 0);
      }
    }
  };

  STAGE(0, 0);
  __syncthreads();
  #pragma unroll 1
  for (int it = 0; it < 16; ++it) {
    if (it < 15) STAGE(((it + 1) & 1) * BUFB, (it + 1) * 64);
    COMPUTE((it & 1) * BUFB);
    __syncthreads();
  }

  // ---- epilogue: D[row][col]: row = lq*4+reg (oc), col = ln (px)   [m89 layout]
  const int y_row = y0 + wv;
  #pragma unroll
  for (int m = 0; m < 4; ++m) {
    #pragma unroll
    for (int r4 = 0; r4 < 4; ++r4) {
      const int oc_l = m * 16 + lq * 4 + r4;
      const float sc = dss[oc_l];
      float* op = out + ((b * 512 + ocb * 64 + oc_l) * 4096 + y_row * 64);
      #pragma unroll
      for (int n = 0; n < 4; ++n)
        op[n * 16 + ln] = acc[m][n][r4] * sc;
    }
  }
}

extern "C" void kernel_launch(void* const* d_in, const int* in_sizes, int n_in,
                              void* d_out, int out_size, void* d_ws, size_t ws_size,
                              hipStream_t stream) {
  const float* x     = (const float*)d_in[0];  // [8,512,64,64]
  const float* style = (const float*)d_in[1];  // [8,512]
  const float* mw    = (const float*)d_in[2];  // [512,512]
  const float* mb    = (const float*)d_in[3];  // [512]
  const float* wsrc  = (const float*)d_in[4];  // [1,512,512,3,3]
  float* out = (float*)d_out;

  char* ws = (char*)d_ws;
  float*  zerobuf = (float*)(ws + 0);          //    64 B (16 f32)
  float*  s       = (float*)(ws + 256);        //  16 KB
  float*  dscale  = (float*)(ws + 16640);      //  16 KB
  float*  wsq     = (float*)(ws + 33024);      //   1 MB
  ushort* wb      = (ushort*)(ws + 1081600);   // 4.5 MB  [9][512][512] bf16
  ushort* xsb     = (ushort*)(ws + 5800192);   //  32 MB  [8][64][64][512] bf16

  hipFuncSetAttribute(reinterpret_cast<const void*>(k_conv),
                      hipFuncAttributeMaxDynamicSharedMemorySize, 2 * BUFB + 256);

  k_style<<<dim3(16), dim3(256), 0, stream>>>(style, mw, mb, s);
  k_wprep<<<dim3(1024), dim3(256), 0, stream>>>(wsrc, wb, wsq, zerobuf);
  k_demod<<<dim3(16), dim3(256), 0, stream>>>(wsq, s, dscale);
  k_xform<<<dim3(64, 8, 2), dim3(256), 0, stream>>>(x, s, xsb);
  k_conv<<<dim3(8, 8, 8), dim3(512), 2 * BUFB + 256, stream>>>(wb, xsb, dscale, zerobuf, out);
}

// Round 3
// 187.187 us; speedup vs baseline: 1.0386x; 1.0161x over previous
//
#include <hip/hip_runtime.h>
#include <hip/hip_bf16.h>

typedef __attribute__((ext_vector_type(8))) short bf16x8;   // 8 bf16 = 4 VGPR
typedef __attribute__((ext_vector_type(4))) float f32x4;
typedef unsigned int u32;

#define MOD_SCALE 0.04419417382415922f     // 1/sqrt(512)
#define CONV_SCALE 0.014731391274719742f   // 1/sqrt(512*9)

__device__ __forceinline__ unsigned short f2bf(float f) {
  union { float f; u32 u; } v; v.f = f;
  u32 r = v.u + 0x7fffu + ((v.u >> 16) & 1u);   // RNE
  return (unsigned short)(r >> 16);
}

__device__ __forceinline__ void gload_lds16(const void* g, void* l) {
  __builtin_amdgcn_global_load_lds(
      (const __attribute__((address_space(1))) u32*)g,
      (__attribute__((address_space(3))) u32*)l, 16, 0, 0);
}

// ---- k_prep: blocks 0..1023 = wprep (wb/wsq/zerobuf), blocks 1024..1039 = style.
__global__ void k_prep(const float* __restrict__ wsrc, ushort* __restrict__ wb,
                       float* __restrict__ wsq, float* __restrict__ zerobuf,
                       const float* __restrict__ style, const float* __restrict__ mw,
                       const float* __restrict__ mb, float* __restrict__ s) {
  if (blockIdx.x < 1024) {
    int idx = blockIdx.x * 256 + threadIdx.x;   // 262144 = oc*512+ic
    if (blockIdx.x == 0 && threadIdx.x < 16) zerobuf[threadIdx.x] = 0.f;
    const float* wp = wsrc + (size_t)idx * 9;
    float sq = 0.f;
    #pragma unroll
    for (int tap = 0; tap < 9; ++tap) {
      float v = wp[tap];
      sq += v * v;
      wb[tap * 262144 + idx] = f2bf(v);
    }
    wsq[idx] = sq;
  } else {
    int idx = (blockIdx.x - 1024) * 256 + threadIdx.x;   // 4096 = b*512+ic
    int b = idx >> 9, ic = idx & 511;
    const float4* wr = (const float4*)(mw + ic * 512);
    const float4* sr = (const float4*)(style + b * 512);
    float acc = 0.f;
    #pragma unroll 4
    for (int k = 0; k < 128; ++k) {
      float4 a = wr[k], c = sr[k];
      acc += a.x * c.x + a.y * c.y + a.z * c.z + a.w * c.w;
    }
    s[idx] = acc * MOD_SCALE + mb[ic];
  }
}

// ---- k3: dscale[b][oc] = CONV_SCALE * rsqrt(CONV_SCALE^2 * sum_ic wsq*s^2 + eps)
__global__ void k_demod(const float* __restrict__ wsq, const float* __restrict__ s,
                        float* __restrict__ dscale) {
  int idx = blockIdx.x * 256 + threadIdx.x;   // 4096 = b*512+oc
  int b = idx >> 9, oc = idx & 511;
  const float4* wq = (const float4*)(wsq + oc * 512);
  const float4* sp = (const float4*)(s + b * 512);
  float acc = 0.f;
  #pragma unroll 4
  for (int k = 0; k < 128; ++k) {
    float4 a = wq[k], c = sp[k];
    acc += a.x * c.x * c.x + a.y * c.y * c.y + a.z * c.z * c.z + a.w * c.w * c.w;
  }
  dscale[idx] = CONV_SCALE * rsqrtf(CONV_SCALE * CONV_SCALE * acc + 1e-8f);
}

// ---- k4: xsb[b][y][x][ic] = bf16(x[b][ic][y][x] * s[b][ic])  (NCHW->NHWC)
__global__ void k_xform(const float* __restrict__ x, const float* __restrict__ s,
                        ushort* __restrict__ xsb) {
  const int y = blockIdx.x, b = blockIdx.y, ich = blockIdx.z;
  const int t = threadIdx.x;
  __shared__ ushort T[64 * 264];          // row stride 264 ushort = 528 B
  const int px = t & 63, iq = t >> 6;
  const int icbase = ich * 256;
  #pragma unroll
  for (int i = 0; i < 8; ++i) {
    int ic8 = i * 4 + iq;                 // 0..31
    int ic0 = icbase + ic8 * 8;
    union { ushort u[8]; uint4 v; } pk;
    #pragma unroll
    for (int j = 0; j < 8; ++j) {
      int ic = ic0 + j;
      float v = x[(b * 512 + ic) * 4096 + y * 64 + px] * s[b * 512 + ic];
      pk.u[j] = f2bf(v);
    }
    *(uint4*)&T[px * 264 + ic8 * 8] = pk.v;
  }
  __syncthreads();
  const int ch = t & 31;
  ushort* obase = xsb + ((b * 64 + y) * 64) * 512 + icbase + ch * 8;
  #pragma unroll
  for (int i = 0; i < 8; ++i) {
    int p = i * 8 + (t >> 5);
    uint4 v = *(const uint4*)&T[p * 264 + ch * 8];
    *(uint4*)(obase + p * 512) = v;
  }
}

// ---- k5: implicit-GEMM conv. 256 threads = 4 waves; block tile 64oc x 8rows x 64px.
// Wave owns 2 adjacent output rows (full 64px x 64oc): acc[2][4][4].
// dy-reuse: per dx, load B-frags for 4 rows once, share across 3 dy taps.
// Per-CU LDS reads/iter: 4x(36A+48B)=336 b128 (~4032cy) < MFMA 5587cy -> MFMA-bound.
// Double-buffered; stage(t+1) before compute(t); one barrier/iter.
#define BUFB 79104
__global__ __launch_bounds__(256, 1) void k_conv(
    const ushort* __restrict__ wb, const ushort* __restrict__ xsb,
    const float* __restrict__ dscale, const float* __restrict__ zerobuf,
    float* __restrict__ out) {
  const int yb = blockIdx.x, ocb = blockIdx.y, b = blockIdx.z;
  const int t = threadIdx.x;
  const int wv = t >> 6, l = t & 63;
  const int ln = l & 15, lq = l >> 4;
  const int y0 = yb * 8;

  extern __shared__ char smem[];
  float* dss = (float*)(smem + 2 * BUFB);

  if (t < 64) dss[t] = dscale[b * 512 + ocb * 64 + t];

  f32x4 acc[2][4][4];
  #pragma unroll
  for (int rr = 0; rr < 2; ++rr)
    #pragma unroll
    for (int m = 0; m < 4; ++m)
      #pragma unroll
      for (int n = 0; n < 4; ++n)
        acc[rr][m][n] = f32x4{0.f, 0.f, 0.f, 0.f};

  const int aslot = lq ^ ((ln >> 1) & 3);
  int bslot[3];
  #pragma unroll
  for (int dx = 0; dx < 3; ++dx) bslot[dx] = lq ^ (((ln + dx) >> 1) & 3);

  // A staging: 2304 chunks = 9 iters x 256 threads (iter i = tap i)
  const int a_ocl = t >> 2;
  const int a_qs = (t & 3) ^ ((a_ocl >> 1) & 3);
  const char* srcA = (const char*)(wb + (ocb * 64 + a_ocl) * 512 + a_qs * 8);
  const int a_dstw = wv * 1024;

  // B staging: 2640 chunks = 10 full iters x 256 + partial 80
  const char* bsrc[11];
  int bdstc[11];
  #pragma unroll
  for (int i = 0; i < 11; ++i) {
    int cid = i * 256 + t;
    int r = cid / 264;
    int rem = cid - r * 264;
    int c = rem >> 2, q = rem & 3;
    int yy = y0 - 1 + r, xx = c - 1;
    int qs = q ^ ((c >> 1) & 3);
    int geo_ok = (cid < 2640) && ((unsigned)yy < 64u) && ((unsigned)xx < 64u);
    bsrc[i] = geo_ok ? (const char*)(xsb + ((b * 64 + yy) * 64 + xx) * 512 + qs * 8)
                     : (const char*)nullptr;
    bdstc[i] = (i * 256 + wv * 64) * 16;
  }

  auto STAGE = [&](int boff, int icB) {
    char* Ab = smem + boff;
    char* Bb = smem + boff + 36864;
    #pragma unroll
    for (int i = 0; i < 9; ++i)
      gload_lds16(srcA + i * 524288 + icB, Ab + i * 4096 + a_dstw);
    #pragma unroll
    for (int i = 0; i < 10; ++i) {
      const char* src = bsrc[i] ? bsrc[i] + icB : (const char*)zerobuf;
      gload_lds16(src, Bb + bdstc[i]);
    }
    if (t < 80) {
      const char* src = bsrc[10] ? bsrc[10] + icB : (const char*)zerobuf;
      gload_lds16(src, Bb + bdstc[10]);
    }
  };

  auto COMPUTE = [&](int boff) {
    const char* Ab = smem + boff;
    const char* Bb = smem + boff + 36864;
    #pragma unroll
    for (int dx = 0; dx < 3; ++dx) {
      bf16x8 bfr[4][4];
      #pragma unroll
      for (int r4 = 0; r4 < 4; ++r4)
        #pragma unroll
        for (int n = 0; n < 4; ++n)
          bfr[r4][n] = *(const bf16x8*)(Bb + ((wv * 2 + r4) * 66 + n * 16 + ln + dx) * 64 + bslot[dx] * 16);
      #pragma unroll
      for (int dy = 0; dy < 3; ++dy) {
        const int tap = dy * 3 + dx;
        bf16x8 af[4];
        #pragma unroll
        for (int m = 0; m < 4; ++m)
          af[m] = *(const bf16x8*)(Ab + tap * 4096 + (m * 16 + ln) * 64 + aslot * 16);
        #pragma unroll
        for (int rr = 0; rr < 2; ++rr)
          #pragma unroll
          for (int m = 0; m < 4; ++m)
            #pragma unroll
            for (int n = 0; n < 4; ++n)
              acc[rr][m][n] = __builtin_amdgcn_mfma_f32_16x16x32_bf16(af[m], bfr[dy + rr][n], acc[rr][m][n], 0, 0, 0);
      }
    }
  };

  STAGE(0, 0);
  __syncthreads();
  #pragma unroll 1
  for (int it = 0; it < 16; ++it) {
    if (it < 15) STAGE(((it + 1) & 1) * BUFB, (it + 1) * 64);
    COMPUTE((it & 1) * BUFB);
    __syncthreads();
  }

  // ---- epilogue: D[row][col]: row = lq*4+reg (oc), col = ln (px)   [m89 layout]
  #pragma unroll
  for (int rr = 0; rr < 2; ++rr) {
    const int y_row = y0 + wv * 2 + rr;
    #pragma unroll
    for (int m = 0; m < 4; ++m) {
      #pragma unroll
      for (int r4 = 0; r4 < 4; ++r4) {
        const int oc_l = m * 16 + lq * 4 + r4;
        const float sc = dss[oc_l];
        float* op = out + ((b * 512 + ocb * 64 + oc_l) * 4096 + y_row * 64);
        #pragma unroll
        for (int n = 0; n < 4; ++n)
          op[n * 16 + ln] = acc[rr][m][n][r4] * sc;
      }
    }
  }
}

extern "C" void kernel_launch(void* const* d_in, const int* in_sizes, int n_in,
                              void* d_out, int out_size, void* d_ws, size_t ws_size,
                              hipStream_t stream) {
  const float* x     = (const float*)d_in[0];  // [8,512,64,64]
  const float* style = (const float*)d_in[1];  // [8,512]
  const float* mw    = (const float*)d_in[2];  // [512,512]
  const float* mb    = (const float*)d_in[3];  // [512]
  const float* wsrc  = (const float*)d_in[4];  // [1,512,512,3,3]
  float* out = (float*)d_out;

  char* ws = (char*)d_ws;
  float*  zerobuf = (float*)(ws + 0);          //    64 B (16 f32)
  float*  s       = (float*)(ws + 256);        //  16 KB
  float*  dscale  = (float*)(ws + 16640);      //  16 KB
  float*  wsq     = (float*)(ws + 33024);      //   1 MB
  ushort* wb      = (ushort*)(ws + 1081600);   // 4.5 MB  [9][512][512] bf16
  ushort* xsb     = (ushort*)(ws + 5800192);   //  32 MB  [8][64][64][512] bf16

  hipFuncSetAttribute(reinterpret_cast<const void*>(k_conv),
                      hipFuncAttributeMaxDynamicSharedMemorySize, 2 * BUFB + 256);

  k_prep<<<dim3(1040), dim3(256), 0, stream>>>(wsrc, wb, wsq, zerobuf, style, mw, mb, s);
  k_demod<<<dim3(16), dim3(256), 0, stream>>>(wsq, s, dscale);
  k_xform<<<dim3(64, 8, 2), dim3(256), 0, stream>>>(x, s, xsb);
  k_conv<<<dim3(8, 8, 8), dim3(256), 2 * BUFB + 256, stream>>>(wb, xsb, dscale, zerobuf, out);
}

// Round 4
// 185.566 us; speedup vs baseline: 1.0477x; 1.0087x over previous
//
#include <hip/hip_runtime.h>
#include <hip/hip_bf16.h>

typedef __attribute__((ext_vector_type(8))) short bf16x8;    // 8 bf16 = 4 VGPR
typedef __attribute__((ext_vector_type(16))) float f32x16;   // 32x32 accumulator
typedef unsigned int u32;

#define MOD_SCALE 0.04419417382415922f     // 1/sqrt(512)
#define CONV_SCALE 0.014731391274719742f   // 1/sqrt(512*9)

__device__ __forceinline__ unsigned short f2bf(float f) {
  union { float f; u32 u; } v; v.f = f;
  u32 r = v.u + 0x7fffu + ((v.u >> 16) & 1u);   // RNE
  return (unsigned short)(r >> 16);
}

__device__ __forceinline__ void gload_lds16(const void* g, void* l) {
  __builtin_amdgcn_global_load_lds(
      (const __attribute__((address_space(1))) u32*)g,
      (__attribute__((address_space(3))) u32*)l, 16, 0, 0);
}

// ---- k_prep: blocks 0..1023 = weight prep, blocks 1024..1039 = style GEMV.
// wb layout: [tap 9][icb 32][oc 512][ic 16] bf16 (16-ic blocked for staging).
__global__ void k_prep(const float* __restrict__ wsrc, ushort* __restrict__ wb,
                       float* __restrict__ wsq, float* __restrict__ zerobuf,
                       const float* __restrict__ style, const float* __restrict__ mw,
                       const float* __restrict__ mb, float* __restrict__ s) {
  if (blockIdx.x < 1024) {
    int idx = blockIdx.x * 256 + threadIdx.x;   // 262144 = oc*512+ic
    int oc = idx >> 9, ic = idx & 511;
    int icb = ic >> 4, icr = ic & 15;
    if (blockIdx.x == 0 && threadIdx.x < 16) zerobuf[threadIdx.x] = 0.f;
    const float* wp = wsrc + (size_t)idx * 9;
    float sq = 0.f;
    #pragma unroll
    for (int tap = 0; tap < 9; ++tap) {
      float v = wp[tap];
      sq += v * v;
      wb[((tap * 32 + icb) * 512 + oc) * 16 + icr] = f2bf(v);
    }
    wsq[idx] = sq;
  } else {
    int idx = (blockIdx.x - 1024) * 256 + threadIdx.x;   // 4096 = b*512+ic
    int b = idx >> 9, ic = idx & 511;
    const float4* wr = (const float4*)(mw + ic * 512);
    const float4* sr = (const float4*)(style + b * 512);
    float acc = 0.f;
    #pragma unroll 4
    for (int k = 0; k < 128; ++k) {
      float4 a = wr[k], c = sr[k];
      acc += a.x * c.x + a.y * c.y + a.z * c.z + a.w * c.w;
    }
    s[idx] = acc * MOD_SCALE + mb[ic];
  }
}

// ---- k_demod: dscale[b][oc] = CONV_SCALE * rsqrt(CONV_SCALE^2 * sum_ic wsq*s^2 + eps)
__global__ void k_demod(const float* __restrict__ wsq, const float* __restrict__ s,
                        float* __restrict__ dscale) {
  int idx = blockIdx.x * 256 + threadIdx.x;   // 4096 = b*512+oc
  int b = idx >> 9, oc = idx & 511;
  const float4* wq = (const float4*)(wsq + oc * 512);
  const float4* sp = (const float4*)(s + b * 512);
  float acc = 0.f;
  #pragma unroll 4
  for (int k = 0; k < 128; ++k) {
    float4 a = wq[k], c = sp[k];
    acc += a.x * c.x * c.x + a.y * c.y * c.y + a.z * c.z * c.z + a.w * c.w * c.w;
  }
  dscale[idx] = CONV_SCALE * rsqrtf(CONV_SCALE * CONV_SCALE * acc + 1e-8f);
}

// ---- k_xform: xsb[b][y][icb 32][x 64][ic 16] = bf16(x[b][ic][y][x] * s[b][ic])
// LDS-free: thread (px, icq) packs 16 ic into 32B and stores contiguously.
__global__ void k_xform(const float* __restrict__ x, const float* __restrict__ s,
                        ushort* __restrict__ xsb) {
  const int y = blockIdx.x, b = blockIdx.y;
  const int t = threadIdx.x;
  const int px = t & 63, icq = t >> 6;
  #pragma unroll
  for (int i = 0; i < 8; ++i) {
    int icb = i * 4 + icq;
    union { ushort u[16]; uint4 v[2]; } pk;
    #pragma unroll
    for (int j = 0; j < 16; ++j) {
      int ic = icb * 16 + j;
      float v = x[(b * 512 + ic) * 4096 + y * 64 + px] * s[b * 512 + ic];
      pk.u[j] = f2bf(v);
    }
    ushort* dst = xsb + ((size_t)((b * 64 + y) * 32 + icb) * 64 + px) * 16;
    *(uint4*)dst = pk.v[0];
    *(uint4*)(dst + 8) = pk.v[1];
  }
}

// ---- k_conv: implicit-GEMM conv with mfma_f32_32x32x16_bf16.
// Block: 64oc x 8rows x 64px, 256 thr = 4 waves; wave = 2 rows, acc[2][2][2] f32x16.
// BK=16: LDS/buf = A(9x64x16) 18432B + B(10x66x16) 21120B = 39552B; x2 dbuf = 79KB
// -> 2 blocks/CU, 2 waves/SIMD. All frag reads are contiguous 1KB b128 (no swizzle).
#define ABYTES 18432
#define BBYTES 21120
#define BUFB   39552
__global__ __launch_bounds__(256, 2) void k_conv(
    const ushort* __restrict__ wb, const ushort* __restrict__ xsb,
    const float* __restrict__ dscale, const float* __restrict__ zerobuf,
    float* __restrict__ out) {
  const int yb = blockIdx.x, ocb = blockIdx.y, b = blockIdx.z;
  const int t = threadIdx.x;
  const int wv = t >> 6, l = t & 63;
  const int lc = l & 31, lh = l >> 5;
  const int y0 = yb * 8, oc0 = ocb * 64;

  extern __shared__ char smem[];
  float* dss = (float*)(smem + 2 * BUFB);
  if (t < 64) dss[t] = dscale[b * 512 + oc0 + t];

  f32x16 acc[2][2][2];
  #pragma unroll
  for (int rr = 0; rr < 2; ++rr)
    #pragma unroll
    for (int ocf = 0; ocf < 2; ++ocf)
      #pragma unroll
      for (int pxf = 0; pxf < 2; ++pxf)
        #pragma unroll
        for (int k = 0; k < 16; ++k)
          acc[rr][ocf][pxf][k] = 0.f;

  // A staging: 1152 chunks (4 full iters + t<128). cid -> tap=cid>>7, oc=rem>>1, h=rem&1
  const char* asrc[5];
  #pragma unroll
  for (int i = 0; i < 5; ++i) {
    int cid = i * 256 + t;
    int tap = cid >> 7, rem = cid & 127;
    int oc_l = rem >> 1, h = rem & 1;
    asrc[i] = (const char*)wb + (size_t)tap * 524288 + (oc0 + oc_l) * 32 + h * 16;
  }
  // B staging: 1320 chunks (5 full + t<40). cid -> row r=cid/132, rem: cols 0,65 = zero border
  const char* bsrc[6];
  int bstride[6];
  #pragma unroll
  for (int i = 0; i < 6; ++i) {
    int cid = i * 256 + t;
    int r = cid / 132, rem = cid - r * 132;
    int yy = y0 - 1 + r;
    bool interior = (rem >= 2) && (rem < 130) && ((unsigned)yy < 64u);
    bsrc[i] = interior
        ? (const char*)xsb + (size_t)(b * 64 + yy) * 65536 + (rem - 2) * 16
        : (const char*)zerobuf;
    bstride[i] = interior ? 2048 : 0;
  }

  auto STAGE = [&](int bo, int icb) {
    char* Ab = smem + bo;
    char* Bb = Ab + ABYTES;
    const int aoff = icb * 16384;
    #pragma unroll
    for (int i = 0; i < 4; ++i)
      gload_lds16(asrc[i] + aoff, Ab + i * 4096 + wv * 1024);
    if (t < 128)
      gload_lds16(asrc[4] + aoff, Ab + 16384 + wv * 1024);
    #pragma unroll
    for (int i = 0; i < 5; ++i)
      gload_lds16(bsrc[i] + icb * bstride[i], Bb + i * 4096 + wv * 1024);
    if (t < 40)
      gload_lds16(bsrc[5] + icb * bstride[5], Bb + 20480);
  };

  auto COMPUTE = [&](int bo) {
    const char* Ab = smem + bo;
    const char* Bb = Ab + ABYTES;
    const int arow = lc * 32 + lh * 16;
    #pragma unroll
    for (int dx = 0; dx < 3; ++dx) {
      bf16x8 bfr[4][2];
      #pragma unroll
      for (int j = 0; j < 4; ++j)
        #pragma unroll
        for (int pxf = 0; pxf < 2; ++pxf)
          bfr[j][pxf] = *(const bf16x8*)(Bb + (wv * 2 + j) * 2112 + (pxf * 32 + dx + lc) * 32 + lh * 16);
      #pragma unroll
      for (int dy = 0; dy < 3; ++dy) {
        const int tap = dy * 3 + dx;
        bf16x8 af[2];
        #pragma unroll
        for (int ocf = 0; ocf < 2; ++ocf)
          af[ocf] = *(const bf16x8*)(Ab + tap * 2048 + ocf * 1024 + arow);
        #pragma unroll
        for (int rr = 0; rr < 2; ++rr)
          #pragma unroll
          for (int ocf = 0; ocf < 2; ++ocf)
            #pragma unroll
            for (int pxf = 0; pxf < 2; ++pxf)
              acc[rr][ocf][pxf] = __builtin_amdgcn_mfma_f32_32x32x16_bf16(
                  af[ocf], bfr[rr + dy][pxf], acc[rr][ocf][pxf], 0, 0, 0);
      }
    }
  };

  STAGE(0, 0);
  __syncthreads();
  #pragma unroll 1
  for (int it = 0; it < 32; ++it) {
    if (it < 31) STAGE(((it + 1) & 1) * BUFB, it + 1);
    COMPUTE((it & 1) * BUFB);
    __syncthreads();
  }

  // ---- epilogue: 32x32 D layout [m74/m101]: col(px)=lane&31, row(oc)=(reg&3)+8*(reg>>2)+4*(lane>>5)
  #pragma unroll
  for (int rr = 0; rr < 2; ++rr) {
    const int y_row = y0 + wv * 2 + rr;
    #pragma unroll
    for (int ocf = 0; ocf < 2; ++ocf) {
      #pragma unroll
      for (int pxf = 0; pxf < 2; ++pxf) {
        #pragma unroll
        for (int reg = 0; reg < 16; ++reg) {
          int oc_l = ocf * 32 + (reg & 3) + 8 * (reg >> 2) + 4 * lh;
          out[(size_t)(b * 512 + oc0 + oc_l) * 4096 + y_row * 64 + pxf * 32 + lc]
              = acc[rr][ocf][pxf][reg] * dss[oc_l];
        }
      }
    }
  }
}

extern "C" void kernel_launch(void* const* d_in, const int* in_sizes, int n_in,
                              void* d_out, int out_size, void* d_ws, size_t ws_size,
                              hipStream_t stream) {
  const float* x     = (const float*)d_in[0];  // [8,512,64,64]
  const float* style = (const float*)d_in[1];  // [8,512]
  const float* mw    = (const float*)d_in[2];  // [512,512]
  const float* mb    = (const float*)d_in[3];  // [512]
  const float* wsrc  = (const float*)d_in[4];  // [1,512,512,3,3]
  float* out = (float*)d_out;

  char* ws = (char*)d_ws;
  float*  zerobuf = (float*)(ws + 0);          //    64 B
  float*  s       = (float*)(ws + 256);        //  16 KB
  float*  dscale  = (float*)(ws + 16640);      //  16 KB
  float*  wsq     = (float*)(ws + 33024);      //   1 MB
  ushort* wb      = (ushort*)(ws + 1081600);   // 4.5 MB  [9][32][512][16] bf16
  ushort* xsb     = (ushort*)(ws + 5800192);   //  32 MB  [8][64][32][64][16] bf16

  hipFuncSetAttribute(reinterpret_cast<const void*>(k_conv),
                      hipFuncAttributeMaxDynamicSharedMemorySize, 2 * BUFB + 256);

  k_prep<<<dim3(1040), dim3(256), 0, stream>>>(wsrc, wb, wsq, zerobuf, style, mw, mb, s);
  k_demod<<<dim3(16), dim3(256), 0, stream>>>(wsq, s, dscale);
  k_xform<<<dim3(64, 8), dim3(256), 0, stream>>>(x, s, xsb);
  k_conv<<<dim3(8, 8, 8), dim3(256), 2 * BUFB + 256, stream>>>(wb, xsb, dscale, zerobuf, out);
}

// Round 5
// 172.664 us; speedup vs baseline: 1.1259x; 1.0747x over previous
//
#include <hip/hip_runtime.h>
#include <hip/hip_bf16.h>

typedef __attribute__((ext_vector_type(8))) short bf16x8;    // 8 bf16 = 4 VGPR
typedef __attribute__((ext_vector_type(16))) float f32x16;   // 32x32 accumulator
typedef unsigned int u32;

#define MOD_SCALE 0.04419417382415922f     // 1/sqrt(512)
#define CONV_SCALE 0.014731391274719742f   // 1/sqrt(512*9)

__device__ __forceinline__ unsigned short f2bf(float f) {
  union { float f; u32 u; } v; v.f = f;
  u32 r = v.u + 0x7fffu + ((v.u >> 16) & 1u);   // RNE
  return (unsigned short)(r >> 16);
}

__device__ __forceinline__ void gload_lds16(const void* g, void* l) {
  __builtin_amdgcn_global_load_lds(
      (const __attribute__((address_space(1))) u32*)g,
      (__attribute__((address_space(3))) u32*)l, 16, 0, 0);
}

// 16B-chunk bank swizzle: p = c ^ bit3(c)  (involution; spreads 32B-stride reads
// across all 32 banks within each half-wave)
__device__ __forceinline__ int swz(int c) { return c ^ ((c >> 3) & 1); }

// ---- k_prep: blocks 0..1023 = weight prep, blocks 1024..1039 = style GEMV.
// wb layout: [tap 9][icb 32][oc 512][ic 16] bf16.
__global__ void k_prep(const float* __restrict__ wsrc, ushort* __restrict__ wb,
                       float* __restrict__ wsq, float* __restrict__ zerobuf,
                       const float* __restrict__ style, const float* __restrict__ mw,
                       const float* __restrict__ mb, float* __restrict__ s) {
  if (blockIdx.x < 1024) {
    int idx = blockIdx.x * 256 + threadIdx.x;   // 262144 = oc*512+ic
    int oc = idx >> 9, ic = idx & 511;
    int icb = ic >> 4, icr = ic & 15;
    if (blockIdx.x == 0 && threadIdx.x < 16) zerobuf[threadIdx.x] = 0.f;
    const float* wp = wsrc + (size_t)idx * 9;
    float sq = 0.f;
    #pragma unroll
    for (int tap = 0; tap < 9; ++tap) {
      float v = wp[tap];
      sq += v * v;
      wb[((tap * 32 + icb) * 512 + oc) * 16 + icr] = f2bf(v);
    }
    wsq[idx] = sq;
  } else {
    int idx = (blockIdx.x - 1024) * 256 + threadIdx.x;   // 4096 = b*512+ic
    int b = idx >> 9, ic = idx & 511;
    const float4* wr = (const float4*)(mw + ic * 512);
    const float4* sr = (const float4*)(style + b * 512);
    float acc = 0.f;
    #pragma unroll 4
    for (int k = 0; k < 128; ++k) {
      float4 a = wr[k], c = sr[k];
      acc += a.x * c.x + a.y * c.y + a.z * c.z + a.w * c.w;
    }
    s[idx] = acc * MOD_SCALE + mb[ic];
  }
}

// ---- k_xform: xsb[b][y][icb 32][x 64][ic 16] = bf16(x[b][ic][y][x] * s[b][ic])
__global__ void k_xform(const float* __restrict__ x, const float* __restrict__ s,
                        ushort* __restrict__ xsb) {
  const int y = blockIdx.x, b = blockIdx.y;
  const int t = threadIdx.x;
  const int px = t & 63, icq = t >> 6;
  #pragma unroll
  for (int i = 0; i < 8; ++i) {
    int icb = i * 4 + icq;
    union { ushort u[16]; uint4 v[2]; } pk;
    #pragma unroll
    for (int j = 0; j < 16; ++j) {
      int ic = icb * 16 + j;
      float v = x[(b * 512 + ic) * 4096 + y * 64 + px] * s[b * 512 + ic];
      pk.u[j] = f2bf(v);
    }
    ushort* dst = xsb + ((size_t)((b * 64 + y) * 32 + icb) * 64 + px) * 16;
    *(uint4*)dst = pk.v[0];
    *(uint4*)(dst + 8) = pk.v[1];
  }
}

// ---- k_conv: implicit-GEMM conv with mfma_f32_32x32x16_bf16.
// Block: 64oc x 8rows x 64px, 256 thr = 4 waves; wave = 2 rows, acc[2][2][2] f32x16.
// BK=16, double-buffered (2 x 39552B) -> 2 blocks/CU. Chunk-XOR bank swizzle on
// both staging source and fragment reads. Demod computed in prologue from wsq/s.
#define ABYTES 18432
#define BBYTES 21120
#define BUFB   39552
__global__ __launch_bounds__(256, 2) void k_conv(
    const ushort* __restrict__ wb, const ushort* __restrict__ xsb,
    const float* __restrict__ wsq, const float* __restrict__ s,
    const float* __restrict__ zerobuf, float* __restrict__ out) {
  const int yb = blockIdx.x, ocb = blockIdx.y, b = blockIdx.z;
  const int t = threadIdx.x;
  const int wv = t >> 6, l = t & 63;
  const int lc = l & 31, lh = l >> 5;
  const int y0 = yb * 8, oc0 = ocb * 64;

  extern __shared__ char smem[];
  float* red = (float*)(smem + 2 * BUFB);         // 1024 B
  float* dss = (float*)(smem + 2 * BUFB + 1024);  //  256 B

  f32x16 acc[2][2][2];
  #pragma unroll
  for (int rr = 0; rr < 2; ++rr)
    #pragma unroll
    for (int ocf = 0; ocf < 2; ++ocf)
      #pragma unroll
      for (int pxf = 0; pxf < 2; ++pxf)
        #pragma unroll
        for (int k = 0; k < 16; ++k)
          acc[rr][ocf][pxf][k] = 0.f;

  // A staging: 1152 chunks; physical chunk pc -> logical c = swz(pc)
  const char* asrc[5];
  #pragma unroll
  for (int i = 0; i < 5; ++i) {
    int cid = i * 256 + t;
    int tap = cid >> 7, pc = cid & 127;
    int c = swz(pc);
    int oc_l = c >> 1, h = c & 1;
    asrc[i] = (const char*)wb + (size_t)tap * 524288 + (oc0 + oc_l) * 32 + h * 16;
  }
  // B staging: 1320 chunks = 10 rows x 132; logical rem = swz(prem); cols 0,65 zero
  const char* bsrc[6];
  int bstride[6];
  #pragma unroll
  for (int i = 0; i < 6; ++i) {
    int cid = i * 256 + t;
    int pr = cid / 132, prem = cid - pr * 132;
    int lrem = swz(prem);
    int yy = y0 - 1 + pr;
    bool interior = (lrem >= 2) && (lrem < 130) && ((unsigned)yy < 64u);
    bsrc[i] = interior
        ? (const char*)xsb + (size_t)(b * 64 + yy) * 65536 + (lrem - 2) * 16
        : (const char*)zerobuf;
    bstride[i] = interior ? 2048 : 0;
  }

  // fragment-read swizzled offsets (per-thread constants)
  int aswzo; { int c = lc * 2 + lh; aswzo = swz(c) * 16; }
  int bswzo[3][2];
  #pragma unroll
  for (int dx = 0; dx < 3; ++dx)
    #pragma unroll
    for (int pxf = 0; pxf < 2; ++pxf) {
      int c = (pxf * 32 + dx + lc) * 2 + lh;
      bswzo[dx][pxf] = swz(c) * 16;
    }

  auto STAGE = [&](int bo, int icb) {
    char* Ab = smem + bo;
    char* Bb = Ab + ABYTES;
    const int aoff = icb * 16384;
    #pragma unroll
    for (int i = 0; i < 4; ++i)
      gload_lds16(asrc[i] + aoff, Ab + i * 4096 + wv * 1024);
    if (t < 128)
      gload_lds16(asrc[4] + aoff, Ab + 16384 + wv * 1024);
    #pragma unroll
    for (int i = 0; i < 5; ++i)
      gload_lds16(bsrc[i] + icb * bstride[i], Bb + i * 4096 + wv * 1024);
    if (t < 40)
      gload_lds16(bsrc[5] + icb * bstride[5], Bb + 20480);
  };

  auto COMPUTE = [&](int bo) {
    const char* Ab = smem + bo;
    const char* Bb = Ab + ABYTES;
    #pragma unroll
    for (int dx = 0; dx < 3; ++dx) {
      bf16x8 bfr[4][2];
      #pragma unroll
      for (int j = 0; j < 4; ++j)
        #pragma unroll
        for (int pxf = 0; pxf < 2; ++pxf)
          bfr[j][pxf] = *(const bf16x8*)(Bb + (wv * 2 + j) * 2112 + bswzo[dx][pxf]);
      #pragma unroll
      for (int dy = 0; dy < 3; ++dy) {
        const int tap = dy * 3 + dx;
        bf16x8 af[2];
        #pragma unroll
        for (int ocf = 0; ocf < 2; ++ocf)
          af[ocf] = *(const bf16x8*)(Ab + tap * 2048 + ocf * 1024 + aswzo);
        #pragma unroll
        for (int rr = 0; rr < 2; ++rr)
          #pragma unroll
          for (int ocf = 0; ocf < 2; ++ocf)
            #pragma unroll
            for (int pxf = 0; pxf < 2; ++pxf)
              acc[rr][ocf][pxf] = __builtin_amdgcn_mfma_f32_32x32x16_bf16(
                  af[ocf], bfr[rr + dy][pxf], acc[rr][ocf][pxf], 0, 0, 0);
      }
    }
  };

  STAGE(0, 0);

  // demod (fused, overlapped with first stage): dss[oc] = CONV_SCALE *
  //   rsqrt(CONV_SCALE^2 * sum_ic wsq[oc0+oc][ic] * s[b][ic]^2 + eps)
  {
    const int oc_l = t & 63, kq = t >> 6;
    const float4* wq = (const float4*)(wsq + (oc0 + oc_l) * 512) + kq * 32;
    const float4* sp = (const float4*)(s + b * 512) + kq * 32;
    float part = 0.f;
    #pragma unroll 4
    for (int k = 0; k < 32; ++k) {
      float4 a = wq[k], c = sp[k];
      part += a.x * c.x * c.x + a.y * c.y * c.y + a.z * c.z * c.z + a.w * c.w * c.w;
    }
    red[t] = part;
  }
  __syncthreads();
  if (t < 64)
    dss[t] = CONV_SCALE * rsqrtf(
        CONV_SCALE * CONV_SCALE * (red[t] + red[t + 64] + red[t + 128] + red[t + 192]) + 1e-8f);

  #pragma unroll 1
  for (int it = 0; it < 32; it += 2) {
    STAGE(BUFB, it + 1);
    COMPUTE(0);
    __syncthreads();
    if (it < 30) STAGE(0, it + 2);
    COMPUTE(BUFB);
    __syncthreads();
  }

  // ---- epilogue: 32x32 D layout [m74/m101]: col(px)=lane&31, row(oc)=(reg&3)+8*(reg>>2)+4*(lane>>5)
  #pragma unroll
  for (int rr = 0; rr < 2; ++rr) {
    const int y_row = y0 + wv * 2 + rr;
    #pragma unroll
    for (int ocf = 0; ocf < 2; ++ocf) {
      #pragma unroll
      for (int pxf = 0; pxf < 2; ++pxf) {
        #pragma unroll
        for (int reg = 0; reg < 16; ++reg) {
          int oc_l = ocf * 32 + (reg & 3) + 8 * (reg >> 2) + 4 * lh;
          out[(size_t)(b * 512 + oc0 + oc_l) * 4096 + y_row * 64 + pxf * 32 + lc]
              = acc[rr][ocf][pxf][reg] * dss[oc_l];
        }
      }
    }
  }
}

extern "C" void kernel_launch(void* const* d_in, const int* in_sizes, int n_in,
                              void* d_out, int out_size, void* d_ws, size_t ws_size,
                              hipStream_t stream) {
  const float* x     = (const float*)d_in[0];  // [8,512,64,64]
  const float* style = (const float*)d_in[1];  // [8,512]
  const float* mw    = (const float*)d_in[2];  // [512,512]
  const float* mb    = (const float*)d_in[3];  // [512]
  const float* wsrc  = (const float*)d_in[4];  // [1,512,512,3,3]
  float* out = (float*)d_out;

  char* ws = (char*)d_ws;
  float*  zerobuf = (float*)(ws + 0);          //    64 B
  float*  s       = (float*)(ws + 256);        //  16 KB
  float*  wsq     = (float*)(ws + 33024);      //   1 MB
  ushort* wb      = (ushort*)(ws + 1081600);   // 4.5 MB  [9][32][512][16] bf16
  ushort* xsb     = (ushort*)(ws + 5800192);   //  32 MB  [8][64][32][64][16] bf16

  hipFuncSetAttribute(reinterpret_cast<const void*>(k_conv),
                      hipFuncAttributeMaxDynamicSharedMemorySize, 2 * BUFB + 1280);

  k_prep<<<dim3(1040), dim3(256), 0, stream>>>(wsrc, wb, wsq, zerobuf, style, mw, mb, s);
  k_xform<<<dim3(64, 8), dim3(256), 0, stream>>>(x, s, xsb);
  k_conv<<<dim3(8, 8, 8), dim3(256), 2 * BUFB + 1280, stream>>>(wb, xsb, wsq, s, zerobuf, out);
}